// Round 12
// baseline (248.356 us; speedup 1.0000x reference)
//
#include <hip/hip_runtime.h>
#include <stdint.h>

#define TLEN  4096
#define BATCH 128
#define NG    6      // groups: 2 joint-pairs per block; wave = (pair, t-half)
#define TT    256    // output t per tile
#define NIT   4      // tiles per block
#define WROWS 144    // per-wave staged rows: 128 t + 15 halo + 1 pad

typedef short short8 __attribute__((ext_vector_type(8)));
typedef float f32x4 __attribute__((ext_vector_type(4)));
typedef unsigned int uint;

__device__ __forceinline__ unsigned short f2bf(float f) {
    uint u = __float_as_uint(f);
    u += 0x7fffu + ((u >> 16) & 1u);
    return (unsigned short)(u >> 16);
}
__device__ __forceinline__ int reflect(int tg) {
    return tg < 0 ? -tg : (tg >= TLEN ? 2 * TLEN - 2 - tg : tg);
}

// Masked bf16 weight fragments: wf[p][co_l(16)][kk(256)], kk = k*16 + ci_l.
__global__ __launch_bounds__(256) void prep_weights_kernel(
    const float* __restrict__ w, unsigned short* __restrict__ wf)
{
    int e = blockIdx.x * 256 + threadIdx.x;   // 12*16*256 = 49152
    int kk   = e & 255;
    int co_l = (e >> 8) & 15;
    int p    = e >> 12;
    int k    = kk >> 4;
    int ci_l = kk & 15;
    int jo = 2 * p + (co_l >> 3);
    int jn = 2 * p - 1 + (ci_l >> 2);
    int ci_g = 8 * p - 4 + ci_l;
    float v = 0.0f;
    if (k < 15 && jn >= 0 && jn < 24 && jn >= jo - 1 && jn <= jo + 1)
        v = w[((size_t)(16 * p + co_l) * 96 + ci_g) * 15 + k];
    wf[e] = f2bf(v);
}

__global__ __launch_bounds__(256, 3) void skel_conv_kernel(
    const float* __restrict__ x, const unsigned short* __restrict__ wf,
    const float* __restrict__ bias, float* __restrict__ out)
{
    // Per-wave private x tile [WROWS][16 ci] bf16, 48 B row stride (proven
    // conflict-free units {0,8}). Single-buffered: within a wave, tile it+1's
    // ds_writes are issued only after tile it's reads were consumed by MFMA,
    // and lgkmcnt orders writes before tile it+1's reads. NO __syncthreads
    // anywhere: waves free-run and self-stagger (the R6 structure's per-tile
    // barrier phase-locked stage/store/MFMA phases across waves).
    __shared__ __align__(16) unsigned short xlds[4 * WROWS * 24];

    const int tid  = threadIdx.x;
    const int tb0  = blockIdx.x * (TT * NIT);
    const int g    = blockIdx.y;
    const int b    = blockIdx.z;
    const int lane = tid & 63;
    const int wave = tid >> 6;
    const int q    = wave & 1;      // pair within group
    const int h    = wave >> 1;     // 128-t half
    const int p    = 2 * g + q;     // global pair
    const int col  = lane & 15;     // A row (co) / B,D col (t)
    const int hi2  = lane >> 4;     // K sub-block selector

    const int ciW = 8 * p - 4;                       // pair's 16-ci window
    const bool interior = (p >= 1) && (p <= 10);     // window fully in-bounds
    const float* xb = x + (size_t)b * 96 * TLEN;
    unsigned short* mybuf = &xlds[wave * (WROWS * 24)];

    // ---- A fragments (once per block), PINNED in VGPRs ----
    short8 afrag[8];
    {
        const unsigned short* wp = wf + (size_t)(p * 16 + col) * 256 + hi2 * 8;
        #pragma unroll
        for (int s = 0; s < 8; ++s)
            afrag[s] = *reinterpret_cast<const short8*>(wp + s * 32);
    }
    #pragma unroll
    for (int s = 0; s < 8; ++s)
        asm volatile("" : "+v"(afrag[s]));

    // ---- bias (folded into acc init) ----
    const int colb = 4 * hi2;
    float bv[4];
    #pragma unroll
    for (int r = 0; r < 4; ++r) bv[r] = bias[16 * p + colb + r];

    // staging banks: rows lane, lane+64, 128+(lane&15) (bank C written by
    // lanes 0..15 only; other lanes load duplicate addresses — L1-absorbed)
    const int rC = 128 + (lane & 15);
    float vA[16], vB[16], vC[16];

    auto STAGE_ISSUE = [&](int tt0) {
        int tw = tt0 + h * 128 - 7;
        const float* xsA = xb + reflect(tw + lane);
        const float* xsB = xb + reflect(tw + 64 + lane);
        const float* xsC = xb + reflect(tw + rC);
        if (interior) {                              // wave-uniform branch
            #pragma unroll
            for (int c = 0; c < 16; ++c) {
                size_t off = (size_t)(ciW + c) * TLEN;
                vA[c] = xsA[off];
                vB[c] = xsB[off];
                vC[c] = xsC[off];
            }
        } else {
            #pragma unroll
            for (int c = 0; c < 16; ++c) {
                int cg = ciW + c;
                bool ok = (unsigned)cg < 96u;
                size_t off = (size_t)cg * TLEN;
                vA[c] = ok ? xsA[off] : 0.f;
                vB[c] = ok ? xsB[off] : 0.f;
                vC[c] = ok ? xsC[off] : 0.f;
            }
        }
    };

    auto STAGE_WRITE = [&]() {
        uint pa[8], pb[8], pc[8];
        #pragma unroll
        for (int qq = 0; qq < 8; ++qq) {
            pa[qq] = (uint)f2bf(vA[2 * qq]) | ((uint)f2bf(vA[2 * qq + 1]) << 16);
            pb[qq] = (uint)f2bf(vB[2 * qq]) | ((uint)f2bf(vB[2 * qq + 1]) << 16);
            pc[qq] = (uint)f2bf(vC[2 * qq]) | ((uint)f2bf(vC[2 * qq + 1]) << 16);
        }
        *reinterpret_cast<uint4*>(&mybuf[lane * 24 + 0]) = make_uint4(pa[0], pa[1], pa[2], pa[3]);
        *reinterpret_cast<uint4*>(&mybuf[lane * 24 + 8]) = make_uint4(pa[4], pa[5], pa[6], pa[7]);
        *reinterpret_cast<uint4*>(&mybuf[(64 + lane) * 24 + 0]) = make_uint4(pb[0], pb[1], pb[2], pb[3]);
        *reinterpret_cast<uint4*>(&mybuf[(64 + lane) * 24 + 8]) = make_uint4(pb[4], pb[5], pb[6], pb[7]);
        if (lane < 16) {
            *reinterpret_cast<uint4*>(&mybuf[rC * 24 + 0]) = make_uint4(pc[0], pc[1], pc[2], pc[3]);
            *reinterpret_cast<uint4*>(&mybuf[rC * 24 + 8]) = make_uint4(pc[4], pc[5], pc[6], pc[7]);
        }
    };

    // prologue: fill this wave's buffer (no barrier — private)
    STAGE_ISSUE(tb0);
    STAGE_WRITE();

    const int ci0   = 8 * (hi2 & 1);   // lane's 8-ci half of the window
    const int kb    = hi2 >> 1;        // k-tap low bit
    const int rbase = col + kb;        // local row base

    for (int it = 0; it < NIT; ++it) {
        // issue next tile's global loads; sched_barrier pins them above the
        // MFMA phase (R5 lesson: hipcc otherwise re-sinks them).
        if (it + 1 < NIT) STAGE_ISSUE(tb0 + (it + 1) * TT);
        __builtin_amdgcn_sched_barrier(0);

        f32x4 acc[8];
        #pragma unroll
        for (int nf = 0; nf < 8; ++nf)
            acc[nf] = (f32x4){bv[0], bv[1], bv[2], bv[3]};

        #pragma unroll
        for (int s = 0; s < 8; ++s) {
            const unsigned short* bp = &mybuf[(rbase + 2 * s) * 24 + ci0];
            #pragma unroll
            for (int nf = 0; nf < 8; ++nf) {
                short8 bfrag = *reinterpret_cast<const short8*>(bp + nf * (16 * 24));
                acc[nf] = __builtin_amdgcn_mfma_f32_16x16x32_bf16(afrag[s], bfrag, acc[nf], 0, 0, 0);
            }
        }

        // write next tile into the same private buffer (reads of tile it all
        // consumed above; write->read of it+1 ordered by lgkmcnt in-wave)
        if (it + 1 < NIT) STAGE_WRITE();

        // stores last: drain overlaps this wave's next MFMA phase
        float* ob = out + ((size_t)b * 192 + 16 * p + colb) * TLEN
                  + tb0 + it * TT + h * 128 + col;
        #pragma unroll
        for (int nf = 0; nf < 8; ++nf) {
            #pragma unroll
            for (int r = 0; r < 4; ++r)
                ob[(size_t)r * TLEN + nf * 16] = acc[nf][r];
        }
    }
}

extern "C" void kernel_launch(void* const* d_in, const int* in_sizes, int n_in,
                              void* d_out, int out_size, void* d_ws, size_t ws_size,
                              hipStream_t stream) {
    const float* x    = (const float*)d_in[0];
    const float* w    = (const float*)d_in[1];
    const float* bias = (const float*)d_in[2];
    float* out        = (float*)d_out;
    unsigned short* wf = (unsigned short*)d_ws;   // 98304 B

    prep_weights_kernel<<<dim3(192), dim3(256), 0, stream>>>(w, wf);
    skel_conv_kernel<<<dim3(TLEN / (TT * NIT), NG, BATCH), dim3(256), 0, stream>>>(
        x, wf, bias, out);
}

// Round 13
// 139.257 us; speedup vs baseline: 1.7834x; 1.7834x over previous
//
#include <hip/hip_runtime.h>
#include <stdint.h>

#define TLEN  4096
#define BATCH 128
#define NG    6      // groups: 2 joint-pairs (32 co, 24-ci union) per block
#define TT    256    // output t per tile
#define NIT   4      // tiles per block (persistent, double-buffered LDS)
#define ROWS  272    // 256 + 16 halo; rows 270..271 zeroed (tap-15 pad)
#define NWG   (TLEN / (TT * NIT) * NG * BATCH)   // 3072 blocks, 1D grid

typedef short short8 __attribute__((ext_vector_type(8)));
typedef float f32x4 __attribute__((ext_vector_type(4)));
typedef unsigned int uint;

__device__ __forceinline__ unsigned short f2bf(float f) {
    uint u = __float_as_uint(f);
    u += 0x7fffu + ((u >> 16) & 1u);
    return (unsigned short)(u >> 16);
}
__device__ __forceinline__ int reflect(int tg) {
    return tg < 0 ? -tg : (tg >= TLEN ? 2 * TLEN - 2 - tg : tg);
}

// Masked bf16 weight fragments: wf[p][co_l(16)][kk(256)], kk = k*16 + ci_l.
__global__ __launch_bounds__(256) void prep_weights_kernel(
    const float* __restrict__ w, unsigned short* __restrict__ wf)
{
    int e = blockIdx.x * 256 + threadIdx.x;   // 12*16*256 = 49152
    int kk   = e & 255;
    int co_l = (e >> 8) & 15;
    int p    = e >> 12;
    int k    = kk >> 4;
    int ci_l = kk & 15;
    int jo = 2 * p + (co_l >> 3);
    int jn = 2 * p - 1 + (ci_l >> 2);
    int ci_g = 8 * p - 4 + ci_l;
    float v = 0.0f;
    if (k < 15 && jn >= 0 && jn < 24 && jn >= jo - 1 && jn <= jo + 1)
        v = w[((size_t)(16 * p + co_l) * 96 + ci_g) * 15 + k];
    wf[e] = f2bf(v);
}

__global__ __launch_bounds__(256, 3) void skel_conv_kernel(
    const float* __restrict__ x, const unsigned short* __restrict__ wf,
    const float* __restrict__ bias, float* __restrict__ out)
{
    // double-buffered x tile [row][ci_union 24] bf16, 48 B rows
    __shared__ __align__(16) unsigned short xlds[2][ROWS * 24];

    // ---- XCD-aware swizzle (T1): dispatch id -> XCD = id % 8 (round-robin).
    // swz gives each XCD a contiguous 384-block chunk; chunk-local order is
    // g-fastest so same-XCD-concurrent blocks share (b, t-range) with
    // overlapping 24-ci windows -> overlap + halo re-reads become L2 hits.
    const int id  = blockIdx.x;
    const int swz = (id & 7) * (NWG / 8) + (id >> 3);
    const int b   = swz / (NG * 4);                 // 24 blocks per batch
    const int rem = swz - b * (NG * 4);
    const int tx  = rem / NG;
    const int g   = rem - tx * NG;
    const int tb0 = tx * (TT * NIT);

    const int tid  = threadIdx.x;
    const int lane = tid & 63;
    const int wave = tid >> 6;
    const int q     = wave & 1;     // pair within group
    const int thalf = wave >> 1;    // 128-t half
    const int p     = 2 * g + q;    // global pair
    const int col  = lane & 15;     // A row (co) / B,D col (t)
    const int hi2  = lane >> 4;     // K sub-block selector

    const int ciBase = 16 * g - 4;
    const float* xb = x + (size_t)b * 96 * TLEN;

    // ---- A fragments (once per block), PINNED in VGPRs ----
    short8 afrag[8];
    {
        const unsigned short* wp = wf + (size_t)(p * 16 + col) * 256 + hi2 * 8;
        #pragma unroll
        for (int s = 0; s < 8; ++s)
            afrag[s] = *reinterpret_cast<const short8*>(wp + s * 32);
    }
    #pragma unroll
    for (int s = 0; s < 8; ++s)
        asm volatile("" : "+v"(afrag[s]));

    // ---- bias (folded into acc init) ----
    const int colb = 4 * hi2;
    float bv[4];
    #pragma unroll
    for (int r = 0; r < 4; ++r) bv[r] = bias[16 * p + colb + r];

    // halo work: rows 256..271, ci 0..23, coalesced 16-lane strips
    const int hr  = 256 + (tid & 15);
    const int hc0 = tid >> 4;          // 0..15
    const int hc1 = 16 + (tid >> 4);   // valid (<24) iff tid < 128

    // single staging register bank (R6 structure)
    float v[24], hv0, hv1;

    auto STAGE_ISSUE = [&](int tt0) {
        int src = reflect(tt0 - 7 + tid);           // main row = tid (<270)
        const float* xs = xb + src;
        #pragma unroll
        for (int c = 0; c < 24; ++c) {
            int cg = ciBase + c;
            v[c] = ((unsigned)cg < 96u) ? xs[(size_t)cg * TLEN] : 0.f;
        }
        int hsrc = reflect(tt0 - 7 + hr);
        int cg0 = ciBase + hc0;
        hv0 = (hr < 270 && (unsigned)cg0 < 96u) ? xb[(size_t)cg0 * TLEN + hsrc] : 0.f;
        int cg1 = ciBase + hc1;
        hv1 = (tid < 128 && hr < 270 && (unsigned)cg1 < 96u) ? xb[(size_t)cg1 * TLEN + hsrc] : 0.f;
    };

    auto STAGE_WRITE = [&](unsigned short* buf) {
        uint vals[12];
        #pragma unroll
        for (int qq = 0; qq < 12; ++qq)
            vals[qq] = (uint)f2bf(v[2 * qq]) | ((uint)f2bf(v[2 * qq + 1]) << 16);
        *reinterpret_cast<uint4*>(&buf[tid * 24 + 0])  = make_uint4(vals[0], vals[1], vals[2],  vals[3]);
        *reinterpret_cast<uint4*>(&buf[tid * 24 + 8])  = make_uint4(vals[4], vals[5], vals[6],  vals[7]);
        *reinterpret_cast<uint4*>(&buf[tid * 24 + 16]) = make_uint4(vals[8], vals[9], vals[10], vals[11]);
        buf[hr * 24 + hc0] = f2bf(hv0);
        if (tid < 128) buf[hr * 24 + hc1] = f2bf(hv1);
    };

    // prologue: fill buffer 0
    STAGE_ISSUE(tb0);
    STAGE_WRITE(xlds[0]);
    __syncthreads();

    const int ci0   = 8 * q + 8 * (hi2 & 1);  // pair q's ci window half
    const int kb    = hi2 >> 1;               // k-tap low bit
    const int rbase = thalf * 128 + col + kb;

    #pragma unroll
    for (int it = 0; it < NIT; ++it) {
        const unsigned short* buf = xlds[it & 1];

        // issue next tile's global loads; sched_barrier pins them above the
        // MFMA phase (R5 failure: hipcc re-sank them, serializing phases).
        if (it + 1 < NIT) STAGE_ISSUE(tb0 + (it + 1) * TT);
        __builtin_amdgcn_sched_barrier(0);

        f32x4 acc[8];
        #pragma unroll
        for (int nf = 0; nf < 8; ++nf)
            acc[nf] = (f32x4){bv[0], bv[1], bv[2], bv[3]};

        #pragma unroll
        for (int s = 0; s < 8; ++s) {
            const unsigned short* bp = &buf[(rbase + 2 * s) * 24 + ci0];
            #pragma unroll
            for (int nf = 0; nf < 8; ++nf) {
                short8 bfrag = *reinterpret_cast<const short8*>(bp + nf * (16 * 24));
                acc[nf] = __builtin_amdgcn_mfma_f32_16x16x32_bf16(afrag[s], bfrag, acc[nf], 0, 0, 0);
            }
        }

        // convert + LDS-write the prefetched tile (loads returned under MFMA)
        if (it + 1 < NIT) STAGE_WRITE(xlds[(it + 1) & 1]);
        __syncthreads();

        // stores after the barrier: drain overlaps next tile's MFMA phase
        float* ob = out + ((size_t)b * 192 + 16 * p + colb) * TLEN
                  + tb0 + it * TT + thalf * 128 + col;
        #pragma unroll
        for (int nf = 0; nf < 8; ++nf) {
            #pragma unroll
            for (int r = 0; r < 4; ++r)
                ob[(size_t)r * TLEN + nf * 16] = acc[nf][r];
        }
    }
}

extern "C" void kernel_launch(void* const* d_in, const int* in_sizes, int n_in,
                              void* d_out, int out_size, void* d_ws, size_t ws_size,
                              hipStream_t stream) {
    const float* x    = (const float*)d_in[0];
    const float* w    = (const float*)d_in[1];
    const float* bias = (const float*)d_in[2];
    float* out        = (float*)d_out;
    unsigned short* wf = (unsigned short*)d_ws;   // 98304 B

    prep_weights_kernel<<<dim3(192), dim3(256), 0, stream>>>(w, wf);
    skel_conv_kernel<<<dim3(NWG), dim3(256), 0, stream>>>(x, wf, bias, out);
}